// Round 12
// baseline (2655.710 us; speedup 1.0000x reference)
//
#include <hip/hip_runtime.h>
#include <cstddef>

namespace {

typedef _Float16 half_t;
typedef _Float16 half2_t __attribute__((ext_vector_type(2)));
typedef _Float16 f16x4 __attribute__((ext_vector_type(4)));
typedef _Float16 f16x8 __attribute__((ext_vector_type(8)));
typedef float f32x4 __attribute__((ext_vector_type(4)));

constexpr int NB = 256;  // batch
constexpr int NT = 512;  // time
constexpr int NH = 128;  // hidden
constexpr int NG = 512;  // 4*NH gates

__device__ __forceinline__ float sigm(float x) { return 1.0f / (1.0f + __expf(-x)); }
__device__ __forceinline__ float tanh_(float x) { return 2.0f / (1.0f + __expf(-2.0f * x)) - 1.0f; }
__device__ __forceinline__ float dot4(float4 w, float4 v, float acc) {
  return fmaf(w.x, v.x, fmaf(w.y, v.y, fmaf(w.z, v.z, fmaf(w.w, v.w, acc))));
}
__device__ __forceinline__ float fdot2(half2_t a, half2_t b, float c) {
  return __builtin_amdgcn_fdot2(a, b, c, false);  // v_dot2_f32_f16, f32 accum
}
__device__ __forceinline__ void pinv8(f16x8& x) { asm volatile("" : "+v"(x)); }

// 8-lane sum, all on the VALU: quad_perm xor1, xor2, then row_half_mirror
// (0x141) exchanges the two quads within each 8-lane group.
__device__ __forceinline__ float r8sum(float v) {
  int t = __builtin_amdgcn_update_dpp(0, __float_as_int(v), 0xB1, 0xF, 0xF, true);   // [1,0,3,2]
  v += __int_as_float(t);
  t = __builtin_amdgcn_update_dpp(0, __float_as_int(v), 0x4E, 0xF, 0xF, true);       // [2,3,0,1]
  v += __int_as_float(t);
  t = __builtin_amdgcn_update_dpp(0, __float_as_int(v), 0x141, 0xF, 0xF, true);      // half-mirror
  return v + __int_as_float(t);
}

// fp32 -> fp16 conversion (weight prep)
__global__ void cvt_kernel(const float* __restrict__ s, half_t* __restrict__ d, int n4) {
  int i = blockIdx.x * blockDim.x + threadIdx.x;
  if (i < n4) {
    float4 v = reinterpret_cast<const float4*>(s)[i];
    f16x4 hv = {(half_t)v.x, (half_t)v.y, (half_t)v.z, (half_t)v.w};
    reinterpret_cast<f16x4*>(d)[i] = hv;
  }
}

// ============ MFMA GEMM: C = A[M,K] * B[N,K]^T + biases ============  (r10, validated)
// !F32OUT: B rows permuted at load (orig = (n&3)*128 + (n>>2)) -> unit-interleaved
//          xg output Ch[m*NG+n]; F32OUT: projection Cf[m*Nstr+n].
template <int K, bool AF32, bool F32OUT>
__global__ __launch_bounds__(256) void xg_gemm(
    const void* __restrict__ Ap, const float* __restrict__ Bw,
    const float* __restrict__ b0, const float* __restrict__ b1,
    half_t* __restrict__ Ch, float* __restrict__ Cf, int Nstr)
{
  __shared__ __align__(16) half_t Atile[128 * K];
  __shared__ __align__(16) half_t Btile[64 * K];
  const int tid = threadIdx.x;
  const int m0 = blockIdx.x * 128;
  const int n0 = blockIdx.y * 64;
  char* Ab = (char*)Atile;
  char* Bb = (char*)Btile;

  if (AF32) {
    const float* Af = (const float*)Ap;
    for (int idx = tid; idx < 128 * K / 4; idx += 256) {
      int row = idx / (K / 4), o = idx % (K / 4);
      float4 v = *(const float4*)(Af + (size_t)(m0 + row) * K + 4 * o);
      f16x4 hv = {(half_t)v.x, (half_t)v.y, (half_t)v.z, (half_t)v.w};
      int byte = ((row * K + 4 * o) * 2) ^ ((row & 7) << 4);
      *(f16x4*)(Ab + byte) = hv;
    }
  } else {
    const half_t* Ah = (const half_t*)Ap;
    for (int idx = tid; idx < 128 * K / 8; idx += 256) {
      int row = idx / (K / 8), o = idx % (K / 8);
      uint4 v = *(const uint4*)(Ah + (size_t)(m0 + row) * K + 8 * o);
      int byte = ((row * K + 8 * o) * 2) ^ ((row & 7) << 4);
      *(uint4*)(Ab + byte) = v;
    }
  }
  for (int idx = tid; idx < 64 * K / 4; idx += 256) {
    int row = idx / (K / 4), o = idx % (K / 4);
    int n = n0 + row;
    int src_row = F32OUT ? n : ((n & 3) * 128 + (n >> 2));  // gate-interleave permutation
    float4 v = *(const float4*)(Bw + (size_t)src_row * K + 4 * o);
    f16x4 hv = {(half_t)v.x, (half_t)v.y, (half_t)v.z, (half_t)v.w};
    int byte = ((row * K + 4 * o) * 2) ^ ((row & 7) << 4);
    *(f16x4*)(Bb + byte) = hv;
  }
  __syncthreads();

  const int lane = tid & 63, w = tid >> 6;
  const int r16 = lane & 15, koff = (lane >> 4) * 8;
  f32x4 acc[2][4];
#pragma unroll
  for (int fm = 0; fm < 2; ++fm)
#pragma unroll
    for (int fn = 0; fn < 4; ++fn) acc[fm][fn] = (f32x4){0.f, 0.f, 0.f, 0.f};

#pragma unroll
  for (int ks = 0; ks < K / 32; ++ks) {
    f16x8 a[2], bf[4];
#pragma unroll
    for (int fm = 0; fm < 2; ++fm) {
      int row = w * 32 + fm * 16 + r16;
      int byte = ((row * K + ks * 32 + koff) * 2) ^ ((row & 7) << 4);
      a[fm] = *(const f16x8*)(Ab + byte);
    }
#pragma unroll
    for (int fn = 0; fn < 4; ++fn) {
      int row = fn * 16 + r16;
      int byte = ((row * K + ks * 32 + koff) * 2) ^ ((row & 7) << 4);
      bf[fn] = *(const f16x8*)(Bb + byte);
    }
#pragma unroll
    for (int fm = 0; fm < 2; ++fm)
#pragma unroll
      for (int fn = 0; fn < 4; ++fn)
        acc[fm][fn] = __builtin_amdgcn_mfma_f32_16x16x32_f16(a[fm], bf[fn], acc[fm][fn], 0, 0, 0);
  }

#pragma unroll
  for (int fm = 0; fm < 2; ++fm)
#pragma unroll
    for (int fn = 0; fn < 4; ++fn) {
      int n = n0 + fn * 16 + r16;
      int bidx = F32OUT ? n : ((n & 3) * 128 + (n >> 2));
      float bb = (b0 ? b0[bidx] : 0.f) + (b1 ? b1[bidx] : 0.f);
#pragma unroll
      for (int q = 0; q < 4; ++q) {
        int m = m0 + w * 32 + fm * 16 + (lane >> 4) * 4 + q;
        float val = acc[fm][fn][q] + bb;
        if (F32OUT) Cf[(size_t)m * Nstr + n] = val;
        else        Ch[(size_t)m * NG + n] = (half_t)val;
      }
    }
}

// ============ Recurrent kernel, 8-way k-split ============
// 256 blocks x 1024 threads (16 waves/CU = 4 waves/SIMD), 1 batch/block.
// j = tid>>3 hidden unit, ko = tid&7 k-slice (16 dims). Per thread per step:
// 32 fdot2 (8 chains, depth 4) + 3-level DPP reduce (VALU) + gates + 1 barrier.
// Pinned weights: 4 gates x 16 dims = 8 f16x8 = 32 VGPRs.
// The 85 KB LDS pad forces 1 block/CU at compile time -> VGPR cap 128, so the
// pinned set stays in arch VGPRs (r8's failure: compiler planned 2 blocks/CU,
// cap 64, weights shunted to AGPRs with per-use v_accvgpr_read tax).
// MODE: 0 = xg-stream -> seq-out; 1 = xg-stream -> hT-out; 2 = const-xg -> seq-out
template <int MODE>
__global__ __attribute__((amdgpu_flat_work_group_size(1024, 1024)))
__attribute__((amdgpu_waves_per_eu(4, 4))) void rec_kernel(
    const half_t* __restrict__ xg,     // [NB*NT][NG] fp16, unit-interleaved
    const float* __restrict__ hT_in,   // [NB,NH]        (mode 2)
    const float* __restrict__ WihD,    // [NG,NH] fp32   (mode 2)
    const float* __restrict__ bih, const float* __restrict__ bhh,  // (mode 2)
    const half_t* __restrict__ Whh,    // [NG,NH] fp16
    half_t* __restrict__ seq_out,      // [NB,NT,NH] fp16 (modes 0/2)
    float* __restrict__ hT_out)        // [NB,NH]         (mode 1)
{
  const int b = blockIdx.x;
  const int tid = threadIdx.x;
  const int j = tid >> 3;   // hidden unit [0,128)
  const int ko = tid & 7;   // k-slice    [0,8)

  __shared__ __align__(16) half_t hbuf[2][NH];  // h double-buffer (group reads @32B stride: 2-way, free)
  __shared__ float xgc[NG];                     // mode-2 scratch
  __shared__ float hinf[NH];
  __shared__ char fpad[85 * 1024];              // occupancy clamp: 1 block/CU

  { volatile char* vp = fpad; vp[tid] = 0; }    // keep fpad allocated

  // Pinned weights: Whh[gi*128+j][ko*16 .. +16], 2 f16x8 per gate.
  f16x8 wh8[4][2];
#pragma unroll
  for (int gi = 0; gi < 4; ++gi) {
    const f16x8* p = reinterpret_cast<const f16x8*>(Whh + (size_t)(gi * NH + j) * NH + ko * 16);
    wh8[gi][0] = p[0];
    wh8[gi][1] = p[1];
  }
#pragma unroll
  for (int gi = 0; gi < 4; ++gi) {
    pinv8(wh8[gi][0]);
    pinv8(wh8[gi][1]);
  }

  if (tid < NH) hbuf[0][tid] = (half_t)0.0f;  // h0 = 0 (read at t=0, parity 0)
  float c = 0.0f;                             // c0 (replicated x8 ko lanes)

  float cx[4] = {0.f, 0.f, 0.f, 0.f};  // mode-2 const xg, /8-folded
  if (MODE == 2) {
    if (tid < NH) hinf[tid] = hT_in[(size_t)b * NH + tid];
    __syncthreads();
    if (tid < NG) {
      float a0 = bih[tid] + bhh[tid], a1 = 0.f, a2 = 0.f, a3 = 0.f;
      const float4* wr = (const float4*)(WihD + (size_t)tid * NH);
      const float4* hv = (const float4*)hinf;
#pragma unroll
      for (int k = 0; k < 8; ++k) {
        a0 = dot4(wr[4 * k + 0], hv[4 * k + 0], a0);
        a1 = dot4(wr[4 * k + 1], hv[4 * k + 1], a1);
        a2 = dot4(wr[4 * k + 2], hv[4 * k + 2], a2);
        a3 = dot4(wr[4 * k + 3], hv[4 * k + 3], a3);
      }
      xgc[tid] = (a0 + a1) + (a2 + a3);
    }
    __syncthreads();
    cx[0] = xgc[j] * 0.125f;       cx[1] = xgc[j + 128] * 0.125f;
    cx[2] = xgc[j + 256] * 0.125f; cx[3] = xgc[j + 384] * 0.125f;
  }

  // xg prefetch, depth 2 (named regs; the 8 ko lanes load the same 8 B)
  const half_t* xbase = nullptr;
  f16x4 xqA = {}, xqB = {};
  if (MODE != 2) {
    xbase = xg + ((size_t)b * NT) * NG + (j << 2);
    xqA = *(const f16x4*)(xbase);
    xqB = *(const f16x4*)(xbase + NG);
  }

  __syncthreads();

  auto stepf = [&](int t, int p, f16x4& xq) {
    f16x4 cur = xq;
    if (MODE != 2 && t + 2 < NT)
      xq = *(const f16x4*)(xbase + (size_t)(t + 2) * NG);  // issue early, use in 2 steps

    const f16x8* hv8 = reinterpret_cast<const f16x8*>(&hbuf[p][ko * 16]);

    // 8 independent dot chains (4 gates x 2 halves); xg/8 folded into pa init.
    float pa[4], pb[4];
    if (MODE == 2) {
#pragma unroll
      for (int gi = 0; gi < 4; ++gi) pa[gi] = cx[gi];
    } else {
#pragma unroll
      for (int gi = 0; gi < 4; ++gi) pa[gi] = (float)cur[gi] * 0.125f;
    }
#pragma unroll
    for (int gi = 0; gi < 4; ++gi) pb[gi] = 0.f;

#pragma unroll
    for (int r8 = 0; r8 < 2; ++r8) {
      const f16x8 H = hv8[r8];
      const half2_t h0 = __builtin_shufflevector(H, H, 0, 1);
      const half2_t h1 = __builtin_shufflevector(H, H, 2, 3);
      const half2_t h2 = __builtin_shufflevector(H, H, 4, 5);
      const half2_t h3 = __builtin_shufflevector(H, H, 6, 7);
#pragma unroll
      for (int gi = 0; gi < 4; ++gi) {
        const f16x8 W = wh8[gi][r8];
        float sa = pa[gi], sb = pb[gi];
        sa = fdot2(__builtin_shufflevector(W, W, 0, 1), h0, sa);
        sb = fdot2(__builtin_shufflevector(W, W, 2, 3), h1, sb);
        sa = fdot2(__builtin_shufflevector(W, W, 4, 5), h2, sa);
        sb = fdot2(__builtin_shufflevector(W, W, 6, 7), h3, sb);
        pa[gi] = sa; pb[gi] = sb;
      }
    }
    // 8-lane sum on the VALU (2x quad_perm + row_half_mirror)
    const float a0 = r8sum(pa[0] + pb[0]);
    const float a1 = r8sum(pa[1] + pb[1]);
    const float a2 = r8sum(pa[2] + pb[2]);
    const float a3 = r8sum(pa[3] + pb[3]);

    const float ig = sigm(a0);
    const float fg = sigm(a1);
    const float gg = tanh_(a2);
    const float og = sigm(a3);
    c = fmaf(fg, c, ig * gg);
    const float h = og * tanh_(c);

    if (ko == 0) {
      hbuf[p ^ 1][j] = (half_t)h;
      if (MODE != 1) seq_out[((size_t)b * NT + t) * NH + j] = (half_t)h;
      else if (t == NT - 1) hT_out[(size_t)b * NH + j] = h;
    }
    __syncthreads();
  };

#pragma unroll 1
  for (int t = 0; t < NT; t += 2) {
    stepf(t, 0, xqA);
    stepf(t + 1, 1, xqB);
  }
}

}  // namespace

extern "C" void kernel_launch(void* const* d_in, const int* in_sizes, int n_in,
                              void* d_out, int out_size, void* d_ws, size_t ws_size,
                              hipStream_t stream) {
  (void)in_sizes; (void)n_in; (void)out_size; (void)ws_size;

  const float* x     = (const float*)d_in[0];
  const float* e0Wih = (const float*)d_in[1];
  const float* e0Whh = (const float*)d_in[2];
  const float* e0bih = (const float*)d_in[3];
  const float* e0bhh = (const float*)d_in[4];
  const float* e1Wih = (const float*)d_in[5];
  const float* e1Whh = (const float*)d_in[6];
  const float* e1bih = (const float*)d_in[7];
  const float* e1bhh = (const float*)d_in[8];
  const float* d0Wih = (const float*)d_in[9];
  const float* d0Whh = (const float*)d_in[10];
  const float* d0bih = (const float*)d_in[11];
  const float* d0bhh = (const float*)d_in[12];
  const float* d1Wih = (const float*)d_in[13];
  const float* d1Whh = (const float*)d_in[14];
  const float* d1bih = (const float*)d_in[15];
  const float* d1bhh = (const float*)d_in[16];
  const float* Wout  = (const float*)d_in[17];
  const float* bout  = (const float*)d_in[18];
  float* out = (float*)d_out;

  // ---- workspace: Whh fp16 x4 | seqA fp16 [B*T,128] | xg fp16 [B*T,512] | hT f32 ----
  half_t* whh0 = (half_t*)d_ws;
  half_t* whh1 = whh0 + 512 * 128;
  half_t* whh2 = whh1 + 512 * 128;
  half_t* whh3 = whh2 + 512 * 128;
  half_t* seqA = whh3 + 512 * 128;
  half_t* xgb  = seqA + (size_t)NB * NT * NH;
  float*  hT   = (float*)(xgb + (size_t)NB * NT * NG);

  cvt_kernel<<<64, 256, 0, stream>>>(e0Whh, whh0, 512 * 128 / 4);
  cvt_kernel<<<64, 256, 0, stream>>>(e1Whh, whh1, 512 * 128 / 4);
  cvt_kernel<<<64, 256, 0, stream>>>(d0Whh, whh2, 512 * 128 / 4);
  cvt_kernel<<<64, 256, 0, stream>>>(d1Whh, whh3, 512 * 128 / 4);

  const int M = NB * NT;  // 131072
  dim3 gX(M / 128, NG / 64), gP(M / 128, 1), blkG(256);
  dim3 gR(NB), blkR(1024);

  // enc0: xg0 = x @ e0Wih^T + b   (A fp32, K=64) -> rec -> seqA
  xg_gemm<64, true, false><<<gX, blkG, 0, stream>>>(x, e0Wih, e0bih, e0bhh, xgb, nullptr, NG);
  rec_kernel<0><<<gR, blkR, 0, stream>>>(xgb, nullptr, nullptr, nullptr, nullptr, whh0, seqA, nullptr);

  // enc1: xg1 = seqA @ e1Wih^T + b (A fp16, K=128) -> rec -> hT
  xg_gemm<128, false, false><<<gX, blkG, 0, stream>>>(seqA, e1Wih, e1bih, e1bhh, xgb, nullptr, NG);
  rec_kernel<1><<<gR, blkR, 0, stream>>>(xgb, nullptr, nullptr, nullptr, nullptr, whh1, nullptr, hT);

  // dec0: const xg from hT -> rec -> seqA
  rec_kernel<2><<<gR, blkR, 0, stream>>>(nullptr, hT, d0Wih, d0bih, d0bhh, whh2, seqA, nullptr);

  // dec1: xg3 = seqA @ d1Wih^T + b -> rec -> seqA (h-seq)
  xg_gemm<128, false, false><<<gX, blkG, 0, stream>>>(seqA, d1Wih, d1bih, d1bhh, xgb, nullptr, NG);
  rec_kernel<0><<<gR, blkR, 0, stream>>>(xgb, nullptr, nullptr, nullptr, nullptr, whh3, seqA, nullptr);

  // projection: out = seqA @ Wout^T + bout (fp32 out, N=64)
  xg_gemm<128, false, true><<<gP, blkG, 0, stream>>>(seqA, Wout, bout, nullptr, nullptr, out, 64);
}

// Round 13
// 1807.241 us; speedup vs baseline: 1.4695x; 1.4695x over previous
//
#include <hip/hip_runtime.h>
#include <cstddef>

namespace {

typedef _Float16 half_t;
typedef _Float16 half2_t __attribute__((ext_vector_type(2)));
typedef _Float16 f16x4 __attribute__((ext_vector_type(4)));
typedef _Float16 f16x8 __attribute__((ext_vector_type(8)));
typedef float f32x4 __attribute__((ext_vector_type(4)));

constexpr int NB = 256;  // batch
constexpr int NT = 512;  // time
constexpr int NH = 128;  // hidden
constexpr int NG = 512;  // 4*NH gates

__device__ __forceinline__ float sigm(float x) { return 1.0f / (1.0f + __expf(-x)); }
__device__ __forceinline__ float tanh_(float x) { return 2.0f / (1.0f + __expf(-2.0f * x)) - 1.0f; }
__device__ __forceinline__ float dot4(float4 w, float4 v, float acc) {
  return fmaf(w.x, v.x, fmaf(w.y, v.y, fmaf(w.z, v.z, fmaf(w.w, v.w, acc))));
}
__device__ __forceinline__ float fdot2(half2_t a, half2_t b, float c) {
  return __builtin_amdgcn_fdot2(a, b, c, false);  // v_dot2_f32_f16, f32 accum
}
__device__ __forceinline__ void pinv8(f16x8& x) { asm volatile("" : "+v"(x)); }

// quad (4-lane) sum via DPP quad_perm -- VALU, not LDS pipe.
__device__ __forceinline__ float qreduce(float v) {
  int t = __builtin_amdgcn_update_dpp(0, __float_as_int(v), 0xB1, 0xF, 0xF, true);  // [1,0,3,2]
  v += __int_as_float(t);
  t = __builtin_amdgcn_update_dpp(0, __float_as_int(v), 0x4E, 0xF, 0xF, true);      // [2,3,0,1]
  return v + __int_as_float(t);
}

// fp32 -> fp16 conversion (weight prep)
__global__ void cvt_kernel(const float* __restrict__ s, half_t* __restrict__ d, int n4) {
  int i = blockIdx.x * blockDim.x + threadIdx.x;
  if (i < n4) {
    float4 v = reinterpret_cast<const float4*>(s)[i];
    f16x4 hv = {(half_t)v.x, (half_t)v.y, (half_t)v.z, (half_t)v.w};
    reinterpret_cast<f16x4*>(d)[i] = hv;
  }
}

// ============ MFMA GEMM: C = A[M,K] * B[N,K]^T + biases ============  (r10, validated)
// !F32OUT: B rows permuted at load (orig = (n&3)*128 + (n>>2)) -> unit-interleaved
//          xg output Ch[m*NG+n], PRE-SCALED by 0.25 (quad-sum in rec restores).
// F32OUT : projection Cf[m*Nstr+n], unscaled.
template <int K, bool AF32, bool F32OUT>
__global__ __launch_bounds__(256) void xg_gemm(
    const void* __restrict__ Ap, const float* __restrict__ Bw,
    const float* __restrict__ b0, const float* __restrict__ b1,
    half_t* __restrict__ Ch, float* __restrict__ Cf, int Nstr)
{
  __shared__ __align__(16) half_t Atile[128 * K];
  __shared__ __align__(16) half_t Btile[64 * K];
  const int tid = threadIdx.x;
  const int m0 = blockIdx.x * 128;
  const int n0 = blockIdx.y * 64;
  char* Ab = (char*)Atile;
  char* Bb = (char*)Btile;

  if (AF32) {
    const float* Af = (const float*)Ap;
    for (int idx = tid; idx < 128 * K / 4; idx += 256) {
      int row = idx / (K / 4), o = idx % (K / 4);
      float4 v = *(const float4*)(Af + (size_t)(m0 + row) * K + 4 * o);
      f16x4 hv = {(half_t)v.x, (half_t)v.y, (half_t)v.z, (half_t)v.w};
      int byte = ((row * K + 4 * o) * 2) ^ ((row & 7) << 4);
      *(f16x4*)(Ab + byte) = hv;
    }
  } else {
    const half_t* Ah = (const half_t*)Ap;
    for (int idx = tid; idx < 128 * K / 8; idx += 256) {
      int row = idx / (K / 8), o = idx % (K / 8);
      uint4 v = *(const uint4*)(Ah + (size_t)(m0 + row) * K + 8 * o);
      int byte = ((row * K + 8 * o) * 2) ^ ((row & 7) << 4);
      *(uint4*)(Ab + byte) = v;
    }
  }
  for (int idx = tid; idx < 64 * K / 4; idx += 256) {
    int row = idx / (K / 4), o = idx % (K / 4);
    int n = n0 + row;
    int src_row = F32OUT ? n : ((n & 3) * 128 + (n >> 2));  // gate-interleave permutation
    float4 v = *(const float4*)(Bw + (size_t)src_row * K + 4 * o);
    f16x4 hv = {(half_t)v.x, (half_t)v.y, (half_t)v.z, (half_t)v.w};
    int byte = ((row * K + 4 * o) * 2) ^ ((row & 7) << 4);
    *(f16x4*)(Bb + byte) = hv;
  }
  __syncthreads();

  const int lane = tid & 63, w = tid >> 6;
  const int r16 = lane & 15, koff = (lane >> 4) * 8;
  f32x4 acc[2][4];
#pragma unroll
  for (int fm = 0; fm < 2; ++fm)
#pragma unroll
    for (int fn = 0; fn < 4; ++fn) acc[fm][fn] = (f32x4){0.f, 0.f, 0.f, 0.f};

#pragma unroll
  for (int ks = 0; ks < K / 32; ++ks) {
    f16x8 a[2], bf[4];
#pragma unroll
    for (int fm = 0; fm < 2; ++fm) {
      int row = w * 32 + fm * 16 + r16;
      int byte = ((row * K + ks * 32 + koff) * 2) ^ ((row & 7) << 4);
      a[fm] = *(const f16x8*)(Ab + byte);
    }
#pragma unroll
    for (int fn = 0; fn < 4; ++fn) {
      int row = fn * 16 + r16;
      int byte = ((row * K + ks * 32 + koff) * 2) ^ ((row & 7) << 4);
      bf[fn] = *(const f16x8*)(Bb + byte);
    }
#pragma unroll
    for (int fm = 0; fm < 2; ++fm)
#pragma unroll
      for (int fn = 0; fn < 4; ++fn)
        acc[fm][fn] = __builtin_amdgcn_mfma_f32_16x16x32_f16(a[fm], bf[fn], acc[fm][fn], 0, 0, 0);
  }

#pragma unroll
  for (int fm = 0; fm < 2; ++fm)
#pragma unroll
    for (int fn = 0; fn < 4; ++fn) {
      int n = n0 + fn * 16 + r16;
      int bidx = F32OUT ? n : ((n & 3) * 128 + (n >> 2));
      float bb = (b0 ? b0[bidx] : 0.f) + (b1 ? b1[bidx] : 0.f);
#pragma unroll
      for (int q = 0; q < 4; ++q) {
        int m = m0 + w * 32 + fm * 16 + (lane >> 4) * 4 + q;
        float val = acc[fm][fn][q] + bb;
        if (F32OUT) Cf[(size_t)m * Nstr + n] = val;
        else        Ch[(size_t)m * NG + n] = (half_t)(val * 0.25f);  // pre-scaled for quad-sum
      }
    }
}

// ============ Fused 2-layer recurrent kernel (pipelined) ============
// 256 blocks x 512 threads (8 waves = 2/SIMD), 1 batch/block, j=tid>>2, kq=tid&3.
// Super-step s: L0 computes h0(s) [s<NT]; L1 computes h1(s-1) from
// concat[h1(s-2); h0(s-1)] [s>=1]. One barrier per super-step; 513 steps
// replace two 512-step sweeps.
// DEC output: h1 staged in LDS, dumped coalesced every 8 super-steps
// (r11's per-step scattered 2-B stores suspected for its 960-vs-750 gap).
template <bool DEC>
__global__ __attribute__((amdgpu_flat_work_group_size(512, 512)))
__attribute__((amdgpu_waves_per_eu(2, 2))) void rec_fused(
    const half_t* __restrict__ xg0,    // [NB*NT][NG] unit-interleaved, /4-scaled (enc)
    const float* __restrict__ hT_in,   // [NB,NH]   (dec)
    const float* __restrict__ Wih0_32, // [NG,NH] fp32 (dec: d0Wih)
    const float* __restrict__ b0a, const float* __restrict__ b0b,  // L0 biases (dec)
    const half_t* __restrict__ Whh0,   // [NG,NH] fp16
    const half_t* __restrict__ WhhC,   // [NG,NH] fp16 (L1 recurrent)
    const half_t* __restrict__ WihC,   // [NG,NH] fp16 (L1 input)
    const float* __restrict__ b1a, const float* __restrict__ b1b,  // L1 biases
    half_t* __restrict__ seq_out,      // [NB*NT][NH] (dec)
    float* __restrict__ hT_out)        // [NB,NH]     (enc)
{
  const int b = blockIdx.x;
  const int tid = threadIdx.x;
  const int j = tid >> 2;
  const int kq = tid & 3;

  // quarters padded to 48 halfs (96 B): bases on banks {0,24,16,8} per parity.
  __shared__ __align__(16) half_t h0buf[2][4][48];
  __shared__ __align__(16) half_t h1buf[2][4][48];
  __shared__ __align__(16) half_t hstage[2][8][NH];  // dec h1 staging (4 KB, dbuf)
  __shared__ float xgc[NG];   // dec const-xg scratch
  __shared__ float hinf[NH];

  // L0 recurrent weights: 16 x f16x8 = 64 VGPRs, pinned.
  f16x8 wh0[4][4];
#pragma unroll
  for (int gi = 0; gi < 4; ++gi) {
    const f16x8* p = reinterpret_cast<const f16x8*>(Whh0 + (size_t)(gi * NH + j) * NH + kq * 32);
#pragma unroll
    for (int r = 0; r < 4; ++r) wh0[gi][r] = p[r];
  }
#pragma unroll
  for (int gi = 0; gi < 4; ++gi)
#pragma unroll
    for (int r = 0; r < 4; ++r) pinv8(wh0[gi][r]);

  // L1 concat weights: kq<2 -> WhhC (h1 dims), kq>=2 -> WihC (h0 dims);
  // cols (kq&1)*64..+64. 32 x f16x8 = 128 VGPRs, pinned.
  f16x8 wc[4][8];
  const half_t* cbase = (kq < 2) ? WhhC : WihC;
#pragma unroll
  for (int gi = 0; gi < 4; ++gi) {
    const f16x8* p =
        reinterpret_cast<const f16x8*>(cbase + (size_t)(gi * NH + j) * NH + (kq & 1) * 64);
#pragma unroll
    for (int r = 0; r < 8; ++r) wc[gi][r] = p[r];
  }
#pragma unroll
  for (int gi = 0; gi < 4; ++gi)
#pragma unroll
    for (int r = 0; r < 8; ++r) pinv8(wc[gi][r]);

  float b1g[4];  // L1 bias, /4-folded (quad-sum restores)
#pragma unroll
  for (int gi = 0; gi < 4; ++gi)
    b1g[gi] = (b1a[gi * NH + j] + b1b[gi * NH + j]) * 0.25f;

  if (tid < NH) {  // h0(-1)=0 (parity 1), h1(-1)=0 (parity 1)
    h0buf[1][tid >> 5][tid & 31] = (half_t)0.f;
    h1buf[1][tid >> 5][tid & 31] = (half_t)0.f;
  }

  float c0 = 0.f, c1 = 0.f;
  float cx[4] = {0.f, 0.f, 0.f, 0.f};  // dec L0 const xg, /4-folded

  if (DEC) {
    if (tid < NH) hinf[tid] = hT_in[(size_t)b * NH + tid];
    __syncthreads();
    float a0 = b0a[tid] + b0b[tid], a1 = 0.f, a2 = 0.f, a3 = 0.f;
    const float4* wr = (const float4*)(Wih0_32 + (size_t)tid * NH);
    const float4* hv = (const float4*)hinf;
#pragma unroll
    for (int k = 0; k < 8; ++k) {
      a0 = dot4(wr[4 * k + 0], hv[4 * k + 0], a0);
      a1 = dot4(wr[4 * k + 1], hv[4 * k + 1], a1);
      a2 = dot4(wr[4 * k + 2], hv[4 * k + 2], a2);
      a3 = dot4(wr[4 * k + 3], hv[4 * k + 3], a3);
    }
    xgc[tid] = (a0 + a1) + (a2 + a3);
    __syncthreads();
    cx[0] = xgc[j] * 0.25f;       cx[1] = xgc[j + 128] * 0.25f;
    cx[2] = xgc[j + 256] * 0.25f; cx[3] = xgc[j + 384] * 0.25f;
  }

  // enc L0 xg prefetch, depth 2 (named regs)
  const half_t* xbase = nullptr;
  f16x4 xqA = {}, xqB = {};
  if (!DEC) {
    xbase = xg0 + (size_t)b * NT * NG + (j << 2);
    xqA = *(const f16x4*)(xbase);
    xqB = *(const f16x4*)(xbase + NG);
  }

  __syncthreads();

  auto stepf = [&](int s, f16x4& xq) {
    // ---------- L0: t = s ----------
    if (s < NT) {
      f16x4 cur = xq;
      if (!DEC && s + 2 < NT)
        xq = *(const f16x4*)(xbase + (size_t)(s + 2) * NG);  // issue early

      float pa[4], pb[4];
      if (DEC) {
#pragma unroll
        for (int gi = 0; gi < 4; ++gi) pa[gi] = cx[gi];
      } else {
#pragma unroll
        for (int gi = 0; gi < 4; ++gi) pa[gi] = (float)cur[gi];  // GEMM pre-scaled by 1/4
      }
#pragma unroll
      for (int gi = 0; gi < 4; ++gi) pb[gi] = 0.f;

      const f16x8* hv8 = reinterpret_cast<const f16x8*>(&h0buf[(s + 1) & 1][kq][0]);
#pragma unroll
      for (int r8 = 0; r8 < 4; ++r8) {
        const f16x8 H = hv8[r8];
        const half2_t h0 = __builtin_shufflevector(H, H, 0, 1);
        const half2_t h1 = __builtin_shufflevector(H, H, 2, 3);
        const half2_t h2 = __builtin_shufflevector(H, H, 4, 5);
        const half2_t h3 = __builtin_shufflevector(H, H, 6, 7);
#pragma unroll
        for (int gi = 0; gi < 4; ++gi) {
          const f16x8 W = wh0[gi][r8];
          float sa = pa[gi], sb = pb[gi];
          sa = fdot2(__builtin_shufflevector(W, W, 0, 1), h0, sa);
          sb = fdot2(__builtin_shufflevector(W, W, 2, 3), h1, sb);
          sa = fdot2(__builtin_shufflevector(W, W, 4, 5), h2, sa);
          sb = fdot2(__builtin_shufflevector(W, W, 6, 7), h3, sb);
          pa[gi] = sa; pb[gi] = sb;
        }
      }
      const float a0 = qreduce(pa[0] + pb[0]);
      const float a1 = qreduce(pa[1] + pb[1]);
      const float a2 = qreduce(pa[2] + pb[2]);
      const float a3 = qreduce(pa[3] + pb[3]);

      const float ig = sigm(a0), fg = sigm(a1), gg = tanh_(a2), og = sigm(a3);
      c0 = fmaf(fg, c0, ig * gg);
      const float hh0 = og * tanh_(c0);
      if (kq == 0) h0buf[s & 1][j >> 5][j & 31] = (half_t)hh0;
    }

    // ---------- L1: t1 = s-1, concat [h1(s-2); h0(s-1)] ----------
    if (s >= 1) {
      const half_t* cA = (kq < 2) ? &h1buf[s & 1][2 * (kq & 1)][0]
                                  : &h0buf[(s + 1) & 1][2 * (kq & 1)][0];
      const f16x8* A8 = reinterpret_cast<const f16x8*>(cA);
      const f16x8* B8 = reinterpret_cast<const f16x8*>(cA + 48);  // next quarter

      float pc[4], pd[4];
#pragma unroll
      for (int gi = 0; gi < 4; ++gi) { pc[gi] = b1g[gi]; pd[gi] = 0.f; }

#pragma unroll
      for (int r8 = 0; r8 < 4; ++r8) {
        const f16x8 HA = A8[r8];
        const f16x8 HB = B8[r8];
        const half2_t a0p = __builtin_shufflevector(HA, HA, 0, 1);
        const half2_t a1p = __builtin_shufflevector(HA, HA, 2, 3);
        const half2_t a2p = __builtin_shufflevector(HA, HA, 4, 5);
        const half2_t a3p = __builtin_shufflevector(HA, HA, 6, 7);
        const half2_t b0p = __builtin_shufflevector(HB, HB, 0, 1);
        const half2_t b1p = __builtin_shufflevector(HB, HB, 2, 3);
        const half2_t b2p = __builtin_shufflevector(HB, HB, 4, 5);
        const half2_t b3p = __builtin_shufflevector(HB, HB, 6, 7);
#pragma unroll
        for (int gi = 0; gi < 4; ++gi) {
          const f16x8 WA = wc[gi][r8];
          const f16x8 WB = wc[gi][r8 + 4];
          float sc = pc[gi], sd = pd[gi];
          sc = fdot2(__builtin_shufflevector(WA, WA, 0, 1), a0p, sc);
          sd = fdot2(__builtin_shufflevector(WB, WB, 0, 1), b0p, sd);
          sc = fdot2(__builtin_shufflevector(WA, WA, 2, 3), a1p, sc);
          sd = fdot2(__builtin_shufflevector(WB, WB, 2, 3), b1p, sd);
          sc = fdot2(__builtin_shufflevector(WA, WA, 4, 5), a2p, sc);
          sd = fdot2(__builtin_shufflevector(WB, WB, 4, 5), b2p, sd);
          sc = fdot2(__builtin_shufflevector(WA, WA, 6, 7), a3p, sc);
          sd = fdot2(__builtin_shufflevector(WB, WB, 6, 7), b3p, sd);
          pc[gi] = sc; pd[gi] = sd;
        }
      }
      const float a0 = qreduce(pc[0] + pd[0]);
      const float a1 = qreduce(pc[1] + pd[1]);
      const float a2 = qreduce(pc[2] + pd[2]);
      const float a3 = qreduce(pc[3] + pd[3]);

      const float ig = sigm(a0), fg = sigm(a1), gg = tanh_(a2), og = sigm(a3);
      c1 = fmaf(fg, c1, ig * gg);
      const float hh1 = og * tanh_(c1);

      if (kq == 0) {
        h1buf[(s + 1) & 1][j >> 5][j & 31] = (half_t)hh1;
        if (DEC) {
          const int t1 = s - 1;
          hstage[(t1 >> 3) & 1][t1 & 7][j] = (half_t)hh1;  // staged, dumped every 8
        } else if (s == NT) {
          hT_out[(size_t)b * NH + j] = hh1;
        }
      }
    }
    __syncthreads();

    // coalesced dump of 8 staged timesteps (dec): 512 threads x 1 dword
    if (DEC && s >= 8 && ((s - 1) & 7) == 7) {
      const int t_base = s - 8;
      const int pbuf = ((s - 1) >> 3) & 1;
      const int r = tid >> 6, u = tid & 63;
      const unsigned int* src = reinterpret_cast<const unsigned int*>(&hstage[pbuf][r][0]);
      *reinterpret_cast<unsigned int*>(seq_out + ((size_t)b * NT + t_base + r) * NH + u * 2) =
          src[u];
      // no extra barrier: next writes target the other parity; this parity is
      // rewritten 8+ super-steps (8+ barriers) later.
    }
  };

#pragma unroll 1
  for (int s = 0; s < NT; s += 2) {
    stepf(s, xqA);
    stepf(s + 1, xqB);
  }
  stepf(NT, xqA);  // drain: L1 computes t1 = NT-1 (L0 guarded off); final dump inside
}

}  // namespace

extern "C" void kernel_launch(void* const* d_in, const int* in_sizes, int n_in,
                              void* d_out, int out_size, void* d_ws, size_t ws_size,
                              hipStream_t stream) {
  (void)in_sizes; (void)n_in; (void)out_size; (void)ws_size;

  const float* x     = (const float*)d_in[0];
  const float* e0Wih = (const float*)d_in[1];
  const float* e0Whh = (const float*)d_in[2];
  const float* e0bih = (const float*)d_in[3];
  const float* e0bhh = (const float*)d_in[4];
  const float* e1Wih = (const float*)d_in[5];
  const float* e1Whh = (const float*)d_in[6];
  const float* e1bih = (const float*)d_in[7];
  const float* e1bhh = (const float*)d_in[8];
  const float* d0Wih = (const float*)d_in[9];
  const float* d0Whh = (const float*)d_in[10];
  const float* d0bih = (const float*)d_in[11];
  const float* d0bhh = (const float*)d_in[12];
  const float* d1Wih = (const float*)d_in[13];
  const float* d1Whh = (const float*)d_in[14];
  const float* d1bih = (const float*)d_in[15];
  const float* d1bhh = (const float*)d_in[16];
  const float* Wout  = (const float*)d_in[17];
  const float* bout  = (const float*)d_in[18];
  float* out = (float*)d_out;

  // ws: 6 fp16 weight arrays | seqA fp16 [B*T,128] | xg0 fp16 [B*T,512] | hT f32
  half_t* whh0h = (half_t*)d_ws;
  half_t* whh1h = whh0h + 512 * 128;
  half_t* wih1h = whh1h + 512 * 128;
  half_t* whh2h = wih1h + 512 * 128;
  half_t* whh3h = whh2h + 512 * 128;
  half_t* wih3h = whh3h + 512 * 128;
  half_t* seqA  = wih3h + 512 * 128;
  half_t* xg0   = seqA + (size_t)NB * NT * NH;
  float*  hT    = (float*)(xg0 + (size_t)NB * NT * NG);

  cvt_kernel<<<64, 256, 0, stream>>>(e0Whh, whh0h, 512 * 128 / 4);
  cvt_kernel<<<64, 256, 0, stream>>>(e1Whh, whh1h, 512 * 128 / 4);
  cvt_kernel<<<64, 256, 0, stream>>>(e1Wih, wih1h, 512 * 128 / 4);
  cvt_kernel<<<64, 256, 0, stream>>>(d0Whh, whh2h, 512 * 128 / 4);
  cvt_kernel<<<64, 256, 0, stream>>>(d1Whh, whh3h, 512 * 128 / 4);
  cvt_kernel<<<64, 256, 0, stream>>>(d1Wih, wih3h, 512 * 128 / 4);

  const int M = NB * NT;  // 131072
  dim3 gX(M / 128, NG / 64), gP(M / 128, 1), blkG(256);
  dim3 gR(NB), blkR(512);

  // enc0 input GEMM: xg0 = (x @ e0Wih^T + biases)/4 (unit-interleaved)
  xg_gemm<64, true, false><<<gX, blkG, 0, stream>>>(x, e0Wih, e0bih, e0bhh, xg0, nullptr, NG);

  // fused encoder (enc0 + enc1): xg0 -> hT
  rec_fused<false><<<gR, blkR, 0, stream>>>(xg0, nullptr, nullptr, nullptr, nullptr,
                                            whh0h, whh1h, wih1h, e1bih, e1bhh,
                                            nullptr, hT);

  // fused decoder (dec0 + dec1): hT -> seqA (dec1 h-seq, LDS-batched stores)
  rec_fused<true><<<gR, blkR, 0, stream>>>(nullptr, hT, d0Wih, d0bih, d0bhh,
                                           whh2h, whh3h, wih3h, d1bih, d1bhh,
                                           seqA, nullptr);

  // projection: out[b][t][f] = seqA @ Wout^T + bout
  xg_gemm<128, false, true><<<gP, blkG, 0, stream>>>(seqA, Wout, bout, nullptr, nullptr, out, 64);
}